// Round 4
// baseline (954.013 us; speedup 1.0000x reference)
//
#include <hip/hip_runtime.h>
#include <math.h>

#define NN 20000
#define H 256
#define R 64
#define EE 320000
#define LN_EPS 1e-5f

using short8 = __attribute__((ext_vector_type(8))) short;
using f32x4  = __attribute__((ext_vector_type(4))) float;

__device__ __forceinline__ float silu_f(float x) { return x / (1.0f + __expf(-x)); }

// round-to-nearest-even fp32 -> bf16 (as ushort)
__device__ __forceinline__ unsigned short f2bf(float f) {
    unsigned u = __float_as_uint(f);
    u += 0x7fff + ((u >> 16) & 1);
    return (unsigned short)(u >> 16);
}
__device__ __forceinline__ float bf2f(unsigned short s) {
    return __uint_as_float(((unsigned)s) << 16);
}

// XOR-swizzled LDS index for [row][64] short arrays: 8-short chunks swizzled by
// (row&7) -> 16B-aligned ds_read_b128 fragments, max 2-way bank conflict, no pad.
__device__ __forceinline__ int sw_idx(int row, int col) {
    return row * 64 + ((((col >> 3) ^ (row & 7)) << 3) | (col & 7));
}

// ---------------------------------------------------------------------------
// K1: fused LayerNorm + Q/K/V projections.  16 nodes per 256-thread block.
// ---------------------------------------------------------------------------
__global__ __launch_bounds__(256) void k_ln_qkv(
    const float* __restrict__ x, const float* __restrict__ g, const float* __restrict__ b,
    const float* __restrict__ Wq, const float* __restrict__ bq,
    const float* __restrict__ Wk, const float* __restrict__ bk,
    const float* __restrict__ Wv, const float* __restrict__ bv,
    float* __restrict__ q, float* __restrict__ k, float* __restrict__ v)
{
    __shared__ float xn[16][H];          // 16 KB
    const int t  = threadIdx.x;
    const int n0 = blockIdx.x * 16;

    #pragma unroll
    for (int i = 0; i < 16; ++i) xn[i][t] = x[(size_t)(n0 + i) * H + t];
    __syncthreads();

    const int n = t >> 4, s = t & 15;
    float sum = 0.f, sq = 0.f;
    #pragma unroll
    for (int j = 0; j < 16; ++j) { float val = xn[n][s + 16 * j]; sum += val; sq += val * val; }
    #pragma unroll
    for (int off = 8; off; off >>= 1) { sum += __shfl_xor(sum, off); sq += __shfl_xor(sq, off); }
    const float mu  = sum * (1.0f / H);
    const float var = sq * (1.0f / H) - mu * mu;
    const float rs  = rsqrtf(var + LN_EPS);
    #pragma unroll
    for (int j = 0; j < 16; ++j) {
        int c = s + 16 * j;
        float val = xn[n][c];
        xn[n][c] = (val - mu) * rs * g[c] + b[c];
    }
    __syncthreads();

    float aq[16], ak[16], av[16];
    #pragma unroll
    for (int i = 0; i < 16; ++i) { aq[i] = 0.f; ak[i] = 0.f; av[i] = 0.f; }
    const float* wqr = Wq + (size_t)t * H;
    const float* wkr = Wk + (size_t)t * H;
    const float* wvr = Wv + (size_t)t * H;
    for (int kk = 0; kk < H; kk += 4) {
        const float4 wq4 = *(const float4*)(wqr + kk);
        const float4 wk4 = *(const float4*)(wkr + kk);
        const float4 wv4 = *(const float4*)(wvr + kk);
        #pragma unroll
        for (int i = 0; i < 16; ++i) {
            const float4 x4 = *(const float4*)&xn[i][kk];
            aq[i] += wq4.x * x4.x + wq4.y * x4.y + wq4.z * x4.z + wq4.w * x4.w;
            ak[i] += wk4.x * x4.x + wk4.y * x4.y + wk4.z * x4.z + wk4.w * x4.w;
            av[i] += wv4.x * x4.x + wv4.y * x4.y + wv4.z * x4.z + wv4.w * x4.w;
        }
    }
    const float bqv = bq[t], bkv = bk[t], bvv = bv[t];
    #pragma unroll
    for (int i = 0; i < 16; ++i) {
        q[(size_t)(n0 + i) * H + t] = aq[i] + bqv;
        k[(size_t)(n0 + i) * H + t] = ak[i] + bkv;
        v[(size_t)(n0 + i) * H + t] = av[i] + bvv;
    }
}

// ---------------------------------------------------------------------------
// Counting sort of edges by dst: hist -> scan -> scatter(perm)
// ---------------------------------------------------------------------------
__global__ __launch_bounds__(256) void k_hist(const int* __restrict__ ei, int* __restrict__ hist) {
    int e = blockIdx.x * 256 + threadIdx.x;
    if (e < EE) atomicAdd(&hist[ei[EE + e]], 1);
}

__global__ __launch_bounds__(1024) void k_scan(const int* __restrict__ hist,
                                               int* __restrict__ cursor) {
    __shared__ int buf[1024];
    __shared__ int carry_s;
    const int t = threadIdx.x;
    if (t == 0) carry_s = 0;
    __syncthreads();
    for (int base = 0; base < NN; base += 1024) {
        int vv = (base + t < NN) ? hist[base + t] : 0;
        buf[t] = vv;
        __syncthreads();
        #pragma unroll
        for (int ofs = 1; ofs < 1024; ofs <<= 1) {
            int add = (t >= ofs) ? buf[t - ofs] : 0;
            __syncthreads();
            buf[t] += add;
            __syncthreads();
        }
        int excl = buf[t] - vv;
        int carry = carry_s;
        if (base + t < NN) cursor[base + t] = carry + excl;
        __syncthreads();
        if (t == 1023) carry_s = carry + buf[1023];
        __syncthreads();
    }
}

__global__ __launch_bounds__(256) void k_scatter(const int* __restrict__ ei,
                                                 int* __restrict__ cursor, int* __restrict__ perm) {
    int e = blockIdx.x * 256 + threadIdx.x;
    if (e < EE) {
        int d = ei[EE + e];
        int pos = atomicAdd(&cursor[d], 1);
        perm[pos] = e;
    }
}

// stage one 128-row h-half of a [256][64] fp32 weight matrix into split-bf16
// LDS (hi/lo), swizzled layout. 2048 float4 chunks / 256 threads = 8 each.
__device__ __forceinline__ void stage_w_half(const float* __restrict__ wsrc,
                                             unsigned short* whi, unsigned short* wlo,
                                             int t) {
    #pragma unroll
    for (int j = 0; j < 8; ++j) {
        const int idx = t + 256 * j;                     // float4 chunk 0..2047
        const float4 x4 = *(const float4*)(wsrc + (size_t)idx * 4);
        const int row = idx >> 4, col = (idx & 15) * 4;
        const int di = sw_idx(row, col);
        const unsigned short h0 = f2bf(x4.x), h1 = f2bf(x4.y),
                             h2 = f2bf(x4.z), h3 = f2bf(x4.w);
        ushort4 hi4 = {h0, h1, h2, h3};
        ushort4 lo4 = {f2bf(x4.x - bf2f(h0)), f2bf(x4.y - bf2f(h1)),
                       f2bf(x4.z - bf2f(h2)), f2bf(x4.w - bf2f(h3))};
        *(ushort4*)&whi[di] = hi4;
        *(ushort4*)&wlo[di] = lo4;
    }
}

// ---------------------------------------------------------------------------
// K2: sorted-edge kernel, split-bf16 MFMA (3x mfma_f32_16x16x32_bf16 per tile
// per k-step; rel err ~2^-17 ~ fp32). Block = 64 sorted edges, 4 waves.
// Wave w owns edge strip [16w,16w+16). A = ea tile (hi/lo in LDS, swizzled),
// B = W^T h-half (hi/lo in LDS). C layout: edge m = quad*4+reg, h = tile*16+nl.
// Attn: per-lane gather q/k + 16-lane shuffle reduce. Scatter: register
// run-flush (sorted dst) -> ~15M scalar atomics (proven round 3).
// ---------------------------------------------------------------------------
__global__ __launch_bounds__(256) void k_edge(
    const float* __restrict__ q, const float* __restrict__ k, const float* __restrict__ v,
    const int* __restrict__ ei, const float* __restrict__ ew, const float* __restrict__ ea,
    const float* __restrict__ Wdk, const float* __restrict__ bdk,
    const float* __restrict__ Wdv, const float* __restrict__ bdv,
    const int* __restrict__ perm,
    float* __restrict__ agg)
{
    __shared__ unsigned short ea_hi_s[64 * 64], ea_lo_s[64 * 64];   //  8+8 KB
    __shared__ unsigned short w_hi_s[128 * 64], w_lo_s[128 * 64];   // 16+16 KB
    __shared__ float attn_s[64];
    __shared__ int src_s[64], dst_s[64];

    const int t    = threadIdx.x;
    const int eb   = blockIdx.x * 64;
    const int lane = t & 63, wave = t >> 6;
    const int nl   = lane & 15, quad = lane >> 4;
    const int estrip = wave * 16;

    if (t < 64) {
        const int e = perm[eb + t];
        src_s[t] = ei[e];
        dst_s[t] = ei[EE + e];
    }
    {   // stage ea tile with on-the-fly hi/lo split; 4 threads per edge row
        const int row = t >> 2, seg = t & 3;
        const int e = perm[eb + row];
        const float* sp = ea + (size_t)e * R + seg * 16;
        #pragma unroll
        for (int j = 0; j < 4; ++j) {
            const float4 x4 = *(const float4*)(sp + 4 * j);
            const int di = sw_idx(row, seg * 16 + 4 * j);
            const unsigned short h0 = f2bf(x4.x), h1 = f2bf(x4.y),
                                 h2 = f2bf(x4.z), h3 = f2bf(x4.w);
            ushort4 hi4 = {h0, h1, h2, h3};
            ushort4 lo4 = {f2bf(x4.x - bf2f(h0)), f2bf(x4.y - bf2f(h1)),
                           f2bf(x4.z - bf2f(h2)), f2bf(x4.w - bf2f(h3))};
            *(ushort4*)&ea_hi_s[di] = hi4;
            *(ushort4*)&ea_lo_s[di] = lo4;
        }
    }
    __syncthreads();

    // A fragments: lane -> A[m = lane&15][k = quad*8+j], persist whole kernel
    short8 a_hi[2], a_lo[2];
    {
        const int arow = estrip + nl;
        #pragma unroll
        for (int ks = 0; ks < 2; ++ks) {
            const int idx = arow * 64 + ((((ks * 4 + quad) ^ (nl & 7)) << 3));
            a_hi[ks] = *(const short8*)&ea_hi_s[idx];
            a_lo[ks] = *(const short8*)&ea_lo_s[idx];
        }
    }
    // per-lane edge meta: 4 consecutive sorted edges (quad*4+reg)
    int d4[4], s4[4];
    #pragma unroll
    for (int r = 0; r < 4; ++r) {
        d4[r] = dst_s[estrip + quad * 4 + r];
        s4[r] = src_s[estrip + quad * 4 + r];
    }

    float part[4] = {0.f, 0.f, 0.f, 0.f};

    // ---------------- pass A: attention logits ----------------
    for (int hh = 0; hh < 2; ++hh) {
        __syncthreads();                       // prior w_s readers done
        stage_w_half(Wdk + (size_t)hh * 128 * R, w_hi_s, w_lo_s, t);
        __syncthreads();
        #pragma unroll
        for (int tt = 0; tt < 8; ++tt) {
            const int wrow = tt * 16 + nl;
            const int hcol = hh * 128 + tt * 16 + nl;
            short8 b_hi[2], b_lo[2];
            #pragma unroll
            for (int ks = 0; ks < 2; ++ks) {
                const int idx = wrow * 64 + ((((ks * 4 + quad) ^ (nl & 7)) << 3));
                b_hi[ks] = *(const short8*)&w_hi_s[idx];
                b_lo[ks] = *(const short8*)&w_lo_s[idx];
            }
            const float bb = bdk[hcol];
            f32x4 acc = {bb, bb, bb, bb};
            #pragma unroll
            for (int ks = 0; ks < 2; ++ks) {
                acc = __builtin_amdgcn_mfma_f32_16x16x32_bf16(a_hi[ks], b_hi[ks], acc, 0, 0, 0);
                acc = __builtin_amdgcn_mfma_f32_16x16x32_bf16(a_lo[ks], b_hi[ks], acc, 0, 0, 0);
                acc = __builtin_amdgcn_mfma_f32_16x16x32_bf16(a_hi[ks], b_lo[ks], acc, 0, 0, 0);
            }
            #pragma unroll
            for (int r = 0; r < 4; ++r) {
                const float dkv = silu_f(acc[r]);
                part[r] += q[(size_t)d4[r] * H + hcol] * k[(size_t)s4[r] * H + hcol] * dkv;
            }
        }
    }
    // reduce over the 16 nl lanes (h within tile); quads untouched
    #pragma unroll
    for (int r = 0; r < 4; ++r) {
        float p = part[r];
        p += __shfl_xor(p, 1); p += __shfl_xor(p, 2);
        p += __shfl_xor(p, 4); p += __shfl_xor(p, 8);
        if (nl == 0) attn_s[estrip + quad * 4 + r] = p;
    }
    __syncthreads();
    if (t < 64) {
        const int e = perm[eb + t];
        const float rr = ew[e];
        const float cut = (rr < 5.0f) ? 0.5f * (__cosf(rr * 0.6283185307f) + 1.0f) : 0.0f;
        attn_s[t] = silu_f(attn_s[t]) * cut;
    }
    __syncthreads();
    float at4[4];
    #pragma unroll
    for (int r = 0; r < 4; ++r) at4[r] = attn_s[estrip + quad * 4 + r];

    // ---------------- pass B: messages + run-flush scatter ----------------
    for (int hh = 0; hh < 2; ++hh) {
        __syncthreads();                       // prior w_s readers done
        stage_w_half(Wdv + (size_t)hh * 128 * R, w_hi_s, w_lo_s, t);
        __syncthreads();
        #pragma unroll
        for (int tt = 0; tt < 8; ++tt) {
            const int wrow = tt * 16 + nl;
            const int hcol = hh * 128 + tt * 16 + nl;
            short8 b_hi[2], b_lo[2];
            #pragma unroll
            for (int ks = 0; ks < 2; ++ks) {
                const int idx = wrow * 64 + ((((ks * 4 + quad) ^ (nl & 7)) << 3));
                b_hi[ks] = *(const short8*)&w_hi_s[idx];
                b_lo[ks] = *(const short8*)&w_lo_s[idx];
            }
            const float bb = bdv[hcol];
            f32x4 acc = {bb, bb, bb, bb};
            #pragma unroll
            for (int ks = 0; ks < 2; ++ks) {
                acc = __builtin_amdgcn_mfma_f32_16x16x32_bf16(a_hi[ks], b_hi[ks], acc, 0, 0, 0);
                acc = __builtin_amdgcn_mfma_f32_16x16x32_bf16(a_lo[ks], b_hi[ks], acc, 0, 0, 0);
                acc = __builtin_amdgcn_mfma_f32_16x16x32_bf16(a_hi[ks], b_lo[ks], acc, 0, 0, 0);
            }
            // register run-flush over this lane's 4 consecutive sorted edges
            float m = 0.f; int cd = -1;
            #pragma unroll
            for (int r = 0; r < 4; ++r) {
                const float dvv = silu_f(acc[r]);
                const float msg = v[(size_t)s4[r] * H + hcol] * dvv * at4[r];
                if (d4[r] != cd) {
                    if (cd >= 0) atomicAdd(&agg[(size_t)cd * H + hcol], m);
                    m = msg; cd = d4[r];
                } else {
                    m += msg;
                }
            }
            atomicAdd(&agg[(size_t)cd * H + hcol], m);
        }
    }
}

// ---------------------------------------------------------------------------
// K3: out = x + agg @ Wo^T + bo.
// ---------------------------------------------------------------------------
__global__ __launch_bounds__(256) void k_out(
    const float* __restrict__ aggm, const float* __restrict__ Wo, const float* __restrict__ bo,
    const float* __restrict__ x, float* __restrict__ out)
{
    __shared__ float ag[16][H];
    const int t  = threadIdx.x;
    const int n0 = blockIdx.x * 16;
    #pragma unroll
    for (int i = 0; i < 16; ++i) ag[i][t] = aggm[(size_t)(n0 + i) * H + t];
    __syncthreads();

    float acc[16];
    #pragma unroll
    for (int i = 0; i < 16; ++i) acc[i] = 0.f;
    const float* wor = Wo + (size_t)t * H;
    for (int kk = 0; kk < H; kk += 4) {
        const float4 w4 = *(const float4*)(wor + kk);
        #pragma unroll
        for (int i = 0; i < 16; ++i) {
            const float4 a4 = *(const float4*)&ag[i][kk];
            acc[i] += w4.x * a4.x + w4.y * a4.y + w4.z * a4.z + w4.w * a4.w;
        }
    }
    const float bov = bo[t];
    #pragma unroll
    for (int i = 0; i < 16; ++i)
        out[(size_t)(n0 + i) * H + t] = x[(size_t)(n0 + i) * H + t] + acc[i] + bov;
}

extern "C" void kernel_launch(void* const* d_in, const int* in_sizes, int n_in,
                              void* d_out, int out_size, void* d_ws, size_t ws_size,
                              hipStream_t stream) {
    const float* x   = (const float*)d_in[0];
    const int*   ei  = (const int*)d_in[1];
    const float* ew  = (const float*)d_in[2];
    const float* ea  = (const float*)d_in[3];
    const float* g   = (const float*)d_in[4];
    const float* b   = (const float*)d_in[5];
    const float* Wq  = (const float*)d_in[6];  const float* bq  = (const float*)d_in[7];
    const float* Wk  = (const float*)d_in[8];  const float* bk  = (const float*)d_in[9];
    const float* Wv  = (const float*)d_in[10]; const float* bv  = (const float*)d_in[11];
    const float* Wo  = (const float*)d_in[12]; const float* bo  = (const float*)d_in[13];
    const float* Wdk = (const float*)d_in[14]; const float* bdk = (const float*)d_in[15];
    const float* Wdv = (const float*)d_in[16]; const float* bdv = (const float*)d_in[17];

    float* q    = (float*)d_ws;
    float* k    = q + (size_t)NN * H;
    float* v    = k + (size_t)NN * H;
    int*   hist = (int*)(v + (size_t)NN * H);
    int*   cur  = hist + NN;
    int*   perm = cur + NN;
    float* agg  = (float*)(perm + EE);

    hipMemsetAsync(hist, 0, NN * sizeof(int), stream);
    hipMemsetAsync(agg, 0, (size_t)NN * H * sizeof(float), stream);
    k_hist<<<EE / 256, 256, 0, stream>>>(ei, hist);
    k_ln_qkv<<<NN / 16, 256, 0, stream>>>(x, g, b, Wq, bq, Wk, bk, Wv, bv, q, k, v);
    k_scan<<<1, 1024, 0, stream>>>(hist, cur);
    k_scatter<<<EE / 256, 256, 0, stream>>>(ei, cur, perm);
    k_edge<<<EE / 64, 256, 0, stream>>>(q, k, v, ei, ew, ea, Wdk, bdk, Wdv, bdv, perm, agg);
    k_out<<<NN / 16, 256, 0, stream>>>(agg, Wo, bo, x, (float*)d_out);
}

// Round 5
// 786.895 us; speedup vs baseline: 1.2124x; 1.2124x over previous
//
#include <hip/hip_runtime.h>
#include <math.h>

#define NN 20000
#define H 256
#define R 64
#define EE 320000
#define LN_EPS 1e-5f
#define NB 79   // ceil(NN/256)

using short8 = __attribute__((ext_vector_type(8))) short;
using f32x4  = __attribute__((ext_vector_type(4))) float;

__device__ __forceinline__ float silu_f(float x) { return x / (1.0f + __expf(-x)); }

// round-to-nearest-even fp32 -> bf16 (as ushort)
__device__ __forceinline__ unsigned short f2bf(float f) {
    unsigned u = __float_as_uint(f);
    u += 0x7fff + ((u >> 16) & 1);
    return (unsigned short)(u >> 16);
}
__device__ __forceinline__ float bf2f(unsigned short s) {
    return __uint_as_float(((unsigned)s) << 16);
}

// XOR-swizzled LDS index for [row][64] short arrays (bf16 fragments)
__device__ __forceinline__ int sw_idx(int row, int col) {
    return row * 64 + ((((col >> 3) ^ (row & 7)) << 3) | (col & 7));
}
// dk/dv scratch [64][128] f32: xor bit4 of col by row-bit2 -> 2-way max on C-store
__device__ __forceinline__ int dk_idx(int row, int col) {
    return row * 128 + (col ^ (((row >> 2) & 1) << 4));
}

// ---------------------------------------------------------------------------
// K1: fused LayerNorm + Q/K/V projections.  16 nodes per 256-thread block.
// ---------------------------------------------------------------------------
__global__ __launch_bounds__(256) void k_ln_qkv(
    const float* __restrict__ x, const float* __restrict__ g, const float* __restrict__ b,
    const float* __restrict__ Wq, const float* __restrict__ bq,
    const float* __restrict__ Wk, const float* __restrict__ bk,
    const float* __restrict__ Wv, const float* __restrict__ bv,
    float* __restrict__ q, float* __restrict__ k, float* __restrict__ v)
{
    __shared__ float xn[16][H];          // 16 KB
    const int t  = threadIdx.x;
    const int n0 = blockIdx.x * 16;

    #pragma unroll
    for (int i = 0; i < 16; ++i) xn[i][t] = x[(size_t)(n0 + i) * H + t];
    __syncthreads();

    const int n = t >> 4, s = t & 15;
    float sum = 0.f, sq = 0.f;
    #pragma unroll
    for (int j = 0; j < 16; ++j) { float val = xn[n][s + 16 * j]; sum += val; sq += val * val; }
    #pragma unroll
    for (int off = 8; off; off >>= 1) { sum += __shfl_xor(sum, off); sq += __shfl_xor(sq, off); }
    const float mu  = sum * (1.0f / H);
    const float var = sq * (1.0f / H) - mu * mu;
    const float rs  = rsqrtf(var + LN_EPS);
    #pragma unroll
    for (int j = 0; j < 16; ++j) {
        int c = s + 16 * j;
        float val = xn[n][c];
        xn[n][c] = (val - mu) * rs * g[c] + b[c];
    }
    __syncthreads();

    float aq[16], ak[16], av[16];
    #pragma unroll
    for (int i = 0; i < 16; ++i) { aq[i] = 0.f; ak[i] = 0.f; av[i] = 0.f; }
    const float* wqr = Wq + (size_t)t * H;
    const float* wkr = Wk + (size_t)t * H;
    const float* wvr = Wv + (size_t)t * H;
    for (int kk = 0; kk < H; kk += 4) {
        const float4 wq4 = *(const float4*)(wqr + kk);
        const float4 wk4 = *(const float4*)(wkr + kk);
        const float4 wv4 = *(const float4*)(wvr + kk);
        #pragma unroll
        for (int i = 0; i < 16; ++i) {
            const float4 x4 = *(const float4*)&xn[i][kk];
            aq[i] += wq4.x * x4.x + wq4.y * x4.y + wq4.z * x4.z + wq4.w * x4.w;
            ak[i] += wk4.x * x4.x + wk4.y * x4.y + wk4.z * x4.z + wk4.w * x4.w;
            av[i] += wv4.x * x4.x + wv4.y * x4.y + wv4.z * x4.z + wv4.w * x4.w;
        }
    }
    const float bqv = bq[t], bkv = bk[t], bvv = bv[t];
    #pragma unroll
    for (int i = 0; i < 16; ++i) {
        q[(size_t)(n0 + i) * H + t] = aq[i] + bqv;
        k[(size_t)(n0 + i) * H + t] = ak[i] + bkv;
        v[(size_t)(n0 + i) * H + t] = av[i] + bvv;
    }
}

// ---------------------------------------------------------------------------
// Counting sort of edges by dst: hist -> 3-phase scan -> scatter(perm)
// ---------------------------------------------------------------------------
__global__ __launch_bounds__(256) void k_hist(const int* __restrict__ ei, int* __restrict__ hist) {
    int e = blockIdx.x * 256 + threadIdx.x;
    if (e < EE) atomicAdd(&hist[ei[EE + e]], 1);
}

// phase 1: per-256-chunk exclusive scan (wave shuffle) + block totals
__global__ __launch_bounds__(256) void k_scan1(const int* __restrict__ hist,
                                               int* __restrict__ cursor, int* __restrict__ bsum) {
    const int t = threadIdx.x, i = blockIdx.x * 256 + t;
    const int lane = t & 63, w = t >> 6;
    const int v = (i < NN) ? hist[i] : 0;
    int incl = v;
    #pragma unroll
    for (int off = 1; off < 64; off <<= 1) {
        int u = __shfl_up(incl, off);
        if (lane >= off) incl += u;
    }
    __shared__ int ws[4];
    if (lane == 63) ws[w] = incl;
    __syncthreads();
    int base = 0;
    #pragma unroll
    for (int j = 0; j < 4; ++j) if (j < w) base += ws[j];
    if (i < NN) cursor[i] = base + incl - v;     // local-exclusive
    if (t == 255) bsum[blockIdx.x] = base + incl;
}

// phase 2: single block exclusive-scans the NB block sums in place
__global__ __launch_bounds__(128) void k_scan2(int* __restrict__ bsum) {
    __shared__ int buf[128];
    const int t = threadIdx.x;
    const int v = (t < NB) ? bsum[t] : 0;
    buf[t] = v;
    __syncthreads();
    #pragma unroll
    for (int off = 1; off < 128; off <<= 1) {
        int add = (t >= off) ? buf[t - off] : 0;
        __syncthreads();
        buf[t] += add;
        __syncthreads();
    }
    if (t < NB) bsum[t] = buf[t] - v;            // exclusive
}

// phase 3: add block base
__global__ __launch_bounds__(256) void k_scan3(int* __restrict__ cursor, const int* __restrict__ bsum) {
    const int i = blockIdx.x * 256 + threadIdx.x;
    if (i < NN) cursor[i] += bsum[blockIdx.x];
}

__global__ __launch_bounds__(256) void k_scatter(const int* __restrict__ ei,
                                                 int* __restrict__ cursor, int* __restrict__ perm) {
    int e = blockIdx.x * 256 + threadIdx.x;
    if (e < EE) {
        int d = ei[EE + e];
        int pos = atomicAdd(&cursor[d], 1);
        perm[pos] = e;
    }
}

// stage one 128-row h-half of a [256][64] fp32 weight matrix into split-bf16
// LDS (hi/lo), swizzled layout. 2048 float4 chunks / 256 threads = 8 each.
__device__ __forceinline__ void stage_w_half(const float* __restrict__ wsrc,
                                             unsigned short* whi, unsigned short* wlo,
                                             int t) {
    #pragma unroll
    for (int j = 0; j < 8; ++j) {
        const int idx = t + 256 * j;                     // float4 chunk 0..2047
        const float4 x4 = *(const float4*)(wsrc + (size_t)idx * 4);
        const int row = idx >> 4, col = (idx & 15) * 4;
        const int di = sw_idx(row, col);
        const unsigned short h0 = f2bf(x4.x), h1 = f2bf(x4.y),
                             h2 = f2bf(x4.z), h3 = f2bf(x4.w);
        ushort4 hi4 = {h0, h1, h2, h3};
        ushort4 lo4 = {f2bf(x4.x - bf2f(h0)), f2bf(x4.y - bf2f(h1)),
                       f2bf(x4.z - bf2f(h2)), f2bf(x4.w - bf2f(h3))};
        *(ushort4*)&whi[di] = hi4;
        *(ushort4*)&wlo[di] = lo4;
    }
}

// ---------------------------------------------------------------------------
// K2: sorted-edge kernel. MFMA core (split-bf16, proven round 4) + coalesced
// float4 epilogues (proven round 3), bridged through LDS: after each MFMA
// half the W-fragment region (dead between halves) is reused as fp32
// dk/dv[64][128] scratch in MFMA C-layout.
// ---------------------------------------------------------------------------
__global__ __launch_bounds__(256, 3) void k_edge(
    const float* __restrict__ q, const float* __restrict__ k, const float* __restrict__ v,
    const int* __restrict__ ei, const float* __restrict__ ew, const float* __restrict__ ea,
    const float* __restrict__ Wdk, const float* __restrict__ bdk,
    const float* __restrict__ Wdv, const float* __restrict__ bdv,
    const int* __restrict__ perm,
    float* __restrict__ agg)
{
    __shared__ unsigned short ea_hi_s[64 * 64], ea_lo_s[64 * 64];   //  8+8 KB
    __shared__ unsigned short w_region[2 * 128 * 64];               // 32 KB
    __shared__ float attn_s[64];
    __shared__ int src_s[64], dst_s[64];

    unsigned short* w_hi_s = w_region;
    unsigned short* w_lo_s = w_region + 128 * 64;
    float* dks = (float*)w_region;                                  // [64][128] f32

    const int t    = threadIdx.x;
    const int eb   = blockIdx.x * 64;
    const int lane = t & 63, wave = t >> 6;
    const int nl   = lane & 15, quad = lane >> 4;
    const int estrip = wave * 16;
    const int tx = t & 31, ty = t >> 5;          // epilogue mapping (round 3)
    const int h0 = tx * 4, e0 = ty * 8;

    if (t < 64) {
        const int e = perm[eb + t];
        src_s[t] = ei[e];
        dst_s[t] = ei[EE + e];
        attn_s[t] = 0.f;
    }
    {   // stage ea tile with on-the-fly hi/lo split; 4 threads per edge row
        const int row = t >> 2, seg = t & 3;
        const int e = perm[eb + row];
        const float* sp = ea + (size_t)e * R + seg * 16;
        #pragma unroll
        for (int j = 0; j < 4; ++j) {
            const float4 x4 = *(const float4*)(sp + 4 * j);
            const int di = sw_idx(row, seg * 16 + 4 * j);
            const unsigned short a0 = f2bf(x4.x), a1 = f2bf(x4.y),
                                 a2 = f2bf(x4.z), a3 = f2bf(x4.w);
            ushort4 hi4 = {a0, a1, a2, a3};
            ushort4 lo4 = {f2bf(x4.x - bf2f(a0)), f2bf(x4.y - bf2f(a1)),
                           f2bf(x4.z - bf2f(a2)), f2bf(x4.w - bf2f(a3))};
            *(ushort4*)&ea_hi_s[di] = hi4;
            *(ushort4*)&ea_lo_s[di] = lo4;
        }
    }
    __syncthreads();

    // A fragments: lane -> A[m = lane&15][k = quad*8+j], persist whole kernel
    short8 a_hi[2], a_lo[2];
    {
        const int arow = estrip + nl;
        #pragma unroll
        for (int ks = 0; ks < 2; ++ks) {
            const int idx = arow * 64 + ((((ks * 4 + quad) ^ (nl & 7)) << 3));
            a_hi[ks] = *(const short8*)&ea_hi_s[idx];
            a_lo[ks] = *(const short8*)&ea_lo_s[idx];
        }
    }

    // ---------------- pass A: attention logits ----------------
    for (int hh = 0; hh < 2; ++hh) {
        __syncthreads();                       // prior readers of w_region done
        stage_w_half(Wdk + (size_t)hh * 128 * R, w_hi_s, w_lo_s, t);
        __syncthreads();

        f32x4 accA[8];
        #pragma unroll
        for (int tt = 0; tt < 8; ++tt) {
            const int wrow = tt * 16 + nl;
            const int hcol = hh * 128 + tt * 16 + nl;
            short8 b_hi[2], b_lo[2];
            #pragma unroll
            for (int ks = 0; ks < 2; ++ks) {
                const int idx = wrow * 64 + ((((ks * 4 + quad) ^ (nl & 7)) << 3));
                b_hi[ks] = *(const short8*)&w_hi_s[idx];
                b_lo[ks] = *(const short8*)&w_lo_s[idx];
            }
            const float bb = bdk[hcol];
            f32x4 acc = {bb, bb, bb, bb};
            #pragma unroll
            for (int ks = 0; ks < 2; ++ks) {
                acc = __builtin_amdgcn_mfma_f32_16x16x32_bf16(a_hi[ks], b_hi[ks], acc, 0, 0, 0);
                acc = __builtin_amdgcn_mfma_f32_16x16x32_bf16(a_lo[ks], b_hi[ks], acc, 0, 0, 0);
                acc = __builtin_amdgcn_mfma_f32_16x16x32_bf16(a_hi[ks], b_lo[ks], acc, 0, 0, 0);
            }
            accA[tt] = acc;
        }
        __syncthreads();                       // all waves done reading w_s
        #pragma unroll
        for (int tt = 0; tt < 8; ++tt)
            #pragma unroll
            for (int r = 0; r < 4; ++r)
                dks[dk_idx(estrip + quad * 4 + r, tt * 16 + nl)] = silu_f(accA[tt][r]);
        __syncthreads();                       // dks ready

        // coalesced epilogue (round-3 pattern): 8 edges x float4 per thread
        #pragma unroll
        for (int i = 0; i < 8; ++i) {
            const int d = dst_s[e0 + i], s = src_s[e0 + i];
            const float4 qi  = *(const float4*)(q + (size_t)d * H + hh * 128 + h0);
            const float4 kj  = *(const float4*)(k + (size_t)s * H + hh * 128 + h0);
            const float4 dk4 = *(const float4*)&dks[dk_idx(e0 + i, h0)];
            float part = qi.x * kj.x * dk4.x + qi.y * kj.y * dk4.y
                       + qi.z * kj.z * dk4.z + qi.w * kj.w * dk4.w;
            #pragma unroll
            for (int off = 16; off; off >>= 1) part += __shfl_xor(part, off);
            if (tx == 0) attn_s[e0 + i] += part;   // same thread both halves
        }
    }
    __syncthreads();
    if (t < 64) {
        const int e = perm[eb + t];
        const float rr = ew[e];
        const float cut = (rr < 5.0f) ? 0.5f * (__cosf(rr * 0.6283185307f) + 1.0f) : 0.0f;
        attn_s[t] = silu_f(attn_s[t]) * cut;
    }

    // ---------------- pass B: messages + run-flush scatter ----------------
    for (int hh = 0; hh < 2; ++hh) {
        __syncthreads();                       // attn final / prior w readers done
        stage_w_half(Wdv + (size_t)hh * 128 * R, w_hi_s, w_lo_s, t);
        __syncthreads();

        f32x4 accA[8];
        #pragma unroll
        for (int tt = 0; tt < 8; ++tt) {
            const int wrow = tt * 16 + nl;
            const int hcol = hh * 128 + tt * 16 + nl;
            short8 b_hi[2], b_lo[2];
            #pragma unroll
            for (int ks = 0; ks < 2; ++ks) {
                const int idx = wrow * 64 + ((((ks * 4 + quad) ^ (nl & 7)) << 3));
                b_hi[ks] = *(const short8*)&w_hi_s[idx];
                b_lo[ks] = *(const short8*)&w_lo_s[idx];
            }
            const float bb = bdv[hcol];
            f32x4 acc = {bb, bb, bb, bb};
            #pragma unroll
            for (int ks = 0; ks < 2; ++ks) {
                acc = __builtin_amdgcn_mfma_f32_16x16x32_bf16(a_hi[ks], b_hi[ks], acc, 0, 0, 0);
                acc = __builtin_amdgcn_mfma_f32_16x16x32_bf16(a_lo[ks], b_hi[ks], acc, 0, 0, 0);
                acc = __builtin_amdgcn_mfma_f32_16x16x32_bf16(a_hi[ks], b_lo[ks], acc, 0, 0, 0);
            }
            accA[tt] = acc;
        }
        __syncthreads();
        #pragma unroll
        for (int tt = 0; tt < 8; ++tt)
            #pragma unroll
            for (int r = 0; r < 4; ++r)
                dks[dk_idx(estrip + quad * 4 + r, tt * 16 + nl)] = silu_f(accA[tt][r]);
        __syncthreads();

        // register run-flush (round 3): dst_s sorted within block
        float4 m = {0.f, 0.f, 0.f, 0.f};
        int cur_d = -1;
        #pragma unroll
        for (int i = 0; i < 8; ++i) {
            const int d = dst_s[e0 + i], s = src_s[e0 + i];
            const float a = attn_s[e0 + i];
            const float4 vj  = *(const float4*)(v + (size_t)s * H + hh * 128 + h0);
            const float4 dv4 = *(const float4*)&dks[dk_idx(e0 + i, h0)];
            float4 mi;
            mi.x = vj.x * dv4.x * a;
            mi.y = vj.y * dv4.y * a;
            mi.z = vj.z * dv4.z * a;
            mi.w = vj.w * dv4.w * a;
            if (d != cur_d) {
                if (cur_d >= 0) {
                    float* dp = agg + (size_t)cur_d * H + hh * 128 + h0;
                    atomicAdd(dp + 0, m.x); atomicAdd(dp + 1, m.y);
                    atomicAdd(dp + 2, m.z); atomicAdd(dp + 3, m.w);
                }
                m = mi; cur_d = d;
            } else {
                m.x += mi.x; m.y += mi.y; m.z += mi.z; m.w += mi.w;
            }
        }
        {
            float* dp = agg + (size_t)cur_d * H + hh * 128 + h0;
            atomicAdd(dp + 0, m.x); atomicAdd(dp + 1, m.y);
            atomicAdd(dp + 2, m.z); atomicAdd(dp + 3, m.w);
        }
    }
}

// ---------------------------------------------------------------------------
// K3: out = x + agg @ Wo^T + bo.
// ---------------------------------------------------------------------------
__global__ __launch_bounds__(256) void k_out(
    const float* __restrict__ aggm, const float* __restrict__ Wo, const float* __restrict__ bo,
    const float* __restrict__ x, float* __restrict__ out)
{
    __shared__ float ag[16][H];
    const int t  = threadIdx.x;
    const int n0 = blockIdx.x * 16;
    #pragma unroll
    for (int i = 0; i < 16; ++i) ag[i][t] = aggm[(size_t)(n0 + i) * H + t];
    __syncthreads();

    float acc[16];
    #pragma unroll
    for (int i = 0; i < 16; ++i) acc[i] = 0.f;
    const float* wor = Wo + (size_t)t * H;
    for (int kk = 0; kk < H; kk += 4) {
        const float4 w4 = *(const float4*)(wor + kk);
        #pragma unroll
        for (int i = 0; i < 16; ++i) {
            const float4 a4 = *(const float4*)&ag[i][kk];
            acc[i] += w4.x * a4.x + w4.y * a4.y + w4.z * a4.z + w4.w * a4.w;
        }
    }
    const float bov = bo[t];
    #pragma unroll
    for (int i = 0; i < 16; ++i)
        out[(size_t)(n0 + i) * H + t] = x[(size_t)(n0 + i) * H + t] + acc[i] + bov;
}

extern "C" void kernel_launch(void* const* d_in, const int* in_sizes, int n_in,
                              void* d_out, int out_size, void* d_ws, size_t ws_size,
                              hipStream_t stream) {
    const float* x   = (const float*)d_in[0];
    const int*   ei  = (const int*)d_in[1];
    const float* ew  = (const float*)d_in[2];
    const float* ea  = (const float*)d_in[3];
    const float* g   = (const float*)d_in[4];
    const float* b   = (const float*)d_in[5];
    const float* Wq  = (const float*)d_in[6];  const float* bq  = (const float*)d_in[7];
    const float* Wk  = (const float*)d_in[8];  const float* bk  = (const float*)d_in[9];
    const float* Wv  = (const float*)d_in[10]; const float* bv  = (const float*)d_in[11];
    const float* Wo  = (const float*)d_in[12]; const float* bo  = (const float*)d_in[13];
    const float* Wdk = (const float*)d_in[14]; const float* bdk = (const float*)d_in[15];
    const float* Wdv = (const float*)d_in[16]; const float* bdv = (const float*)d_in[17];

    float* q    = (float*)d_ws;
    float* k    = q + (size_t)NN * H;
    float* v    = k + (size_t)NN * H;
    int*   hist = (int*)(v + (size_t)NN * H);
    int*   cur  = hist + NN;
    int*   perm = cur + NN;
    int*   bsum = perm + EE;
    float* agg  = (float*)(bsum + NB + 1);

    hipMemsetAsync(hist, 0, NN * sizeof(int), stream);
    hipMemsetAsync(agg, 0, (size_t)NN * H * sizeof(float), stream);
    k_hist<<<EE / 256, 256, 0, stream>>>(ei, hist);
    k_ln_qkv<<<NN / 16, 256, 0, stream>>>(x, g, b, Wq, bq, Wk, bk, Wv, bv, q, k, v);
    k_scan1<<<NB, 256, 0, stream>>>(hist, cur, bsum);
    k_scan2<<<1, 128, 0, stream>>>(bsum);
    k_scan3<<<NB, 256, 0, stream>>>(cur, bsum);
    k_scatter<<<EE / 256, 256, 0, stream>>>(ei, cur, perm);
    k_edge<<<EE / 64, 256, 0, stream>>>(q, k, v, ei, ew, ea, Wdk, bdk, Wdv, bdv, perm, agg);
    k_out<<<NN / 16, 256, 0, stream>>>(agg, Wo, bo, x, (float*)d_out);
}

// Round 6
// 666.804 us; speedup vs baseline: 1.4307x; 1.1801x over previous
//
#include <hip/hip_runtime.h>
#include <math.h>

#define NN 20000
#define H 256
#define R 64
#define EE 320000
#define LN_EPS 1e-5f
#define NB 79   // ceil(NN/256)

using short8  = __attribute__((ext_vector_type(8))) short;
using ushort8 = __attribute__((ext_vector_type(8))) unsigned short;
using f32x4   = __attribute__((ext_vector_type(4))) float;

__device__ __forceinline__ float silu_f(float x) { return x / (1.0f + __expf(-x)); }

// round-to-nearest-even fp32 -> bf16 (as ushort)
__device__ __forceinline__ unsigned short f2bf(float f) {
    unsigned u = __float_as_uint(f);
    u += 0x7fff + ((u >> 16) & 1);
    return (unsigned short)(u >> 16);
}
__device__ __forceinline__ float bf2f(unsigned short s) {
    return __uint_as_float(((unsigned)s) << 16);
}

// XOR-swizzled LDS index for [row][64] short arrays (bf16 fragments)
__device__ __forceinline__ int sw_idx(int row, int col) {
    return row * 64 + ((((col >> 3) ^ (row & 7)) << 3) | (col & 7));
}
// dk/dv scratch [64][128] f32: xor bit4 of col by row-bit2 -> 2-way max on C-store
__device__ __forceinline__ int dk_idx(int row, int col) {
    return row * 128 + (col ^ (((row >> 2) & 1) << 4));
}

// ---------------------------------------------------------------------------
// Prep: pack a [256][256] fp32 weight into split-bf16 MFMA B-fragment order.
// Group (tile,ks) of 1024 shorts: 512 hi then 512 lo; within: lane*8.
// Lane (nl,quad) holds W'[h=tile*16+nl][c=ks*32+quad*8+j], W' = W*g if fold.
// ---------------------------------------------------------------------------
__global__ __launch_bounds__(256) void k_prep_w(
    const float* __restrict__ W, const float* __restrict__ g, int fold,
    unsigned short* __restrict__ out)
{
    const int flat = blockIdx.x * 256 + threadIdx.x;  // [0, 8192)
    const int tile = flat >> 9;
    const int rem  = flat & 511;
    const int ks   = rem >> 6;
    const int lane = rem & 63;
    const int nl = lane & 15, quad = lane >> 4;
    const int h  = tile * 16 + nl;
    const int c0 = ks * 32 + quad * 8;
    short8 hi8, lo8;
    #pragma unroll
    for (int j = 0; j < 8; ++j) {
        float wv = W[(size_t)h * 256 + c0 + j];
        if (fold) wv *= g[c0 + j];
        const unsigned short hh = f2bf(wv);
        hi8[j] = (short)hh;
        lo8[j] = (short)f2bf(wv - bf2f(hh));
    }
    unsigned short* ob = out + ((size_t)(tile * 8 + ks)) * 1024;
    *(short8*)&ob[lane * 8] = hi8;
    *(short8*)&ob[512 + lane * 8] = lo8;
}

// adjusted QKV biases: bias3[mat][h] = b_mat[h] + sum_c b[c] * W_mat[h][c]
__global__ __launch_bounds__(256) void k_prep_bias(
    const float* __restrict__ b,
    const float* __restrict__ Wq, const float* __restrict__ bq,
    const float* __restrict__ Wk, const float* __restrict__ bk,
    const float* __restrict__ Wv, const float* __restrict__ bv,
    float* __restrict__ bias3)
{
    const int h = threadIdx.x, mat = blockIdx.x;
    const float* W  = mat == 0 ? Wq : (mat == 1 ? Wk : Wv);
    const float* bb = mat == 0 ? bq : (mat == 1 ? bk : bv);
    float s = 0.f;
    const float* wr = W + (size_t)h * 256;
    for (int c = 0; c < 256; c += 4) {
        const float4 w4 = *(const float4*)(wr + c);
        const float4 b4 = *(const float4*)(b + c);
        s += w4.x * b4.x + w4.y * b4.y + w4.z * b4.z + w4.w * b4.w;
    }
    bias3[mat * 256 + h] = bb[h] + s;
}

// Prep: pack Wdk/Wdv [256][64] into the exact 32KB-per-half swizzled LDS image
// k_edge uses (hi image 8192 shorts, then lo image 8192 shorts, per h-half).
__global__ __launch_bounds__(256) void k_prep_wdx(
    const float* __restrict__ Wdk, const float* __restrict__ Wdv,
    unsigned short* __restrict__ wdk_p, unsigned short* __restrict__ wdv_p)
{
    const int flat = blockIdx.x * 256 + threadIdx.x;  // [0, 8192)
    const int mat  = flat >> 12;
    const int rem  = flat & 4095;
    const int hh   = rem >> 11;
    const int r2   = rem & 2047;
    const int row  = r2 >> 4;            // [0,128) h-local
    const int col4 = (r2 & 15) * 4;      // [0,64) r, step 4
    const float* W = mat == 0 ? Wdk : Wdv;
    unsigned short* out = (mat == 0 ? wdk_p : wdv_p) + hh * 16384;
    const float4 w4 = *(const float4*)(W + (size_t)(hh * 128 + row) * 64 + col4);
    const unsigned short h0 = f2bf(w4.x), h1 = f2bf(w4.y), h2 = f2bf(w4.z), h3 = f2bf(w4.w);
    ushort4 hi4 = {h0, h1, h2, h3};
    ushort4 lo4 = {f2bf(w4.x - bf2f(h0)), f2bf(w4.y - bf2f(h1)),
                   f2bf(w4.z - bf2f(h2)), f2bf(w4.w - bf2f(h3))};
    const int di = sw_idx(row, col4);
    *(ushort4*)&out[di] = hi4;
    *(ushort4*)&out[8192 + di] = lo4;
}

// ---------------------------------------------------------------------------
// K1: LayerNorm + QKV via split-bf16 MFMA. 64 nodes/block (16/wave), no LDS.
// A frags in registers: lane (nl,quad) holds z[node=strip+nl][c=ks*32+quad*8+j].
// B frags loaded from prepped wqkv_p. C: node=quad*4+reg, h=tile*16+nl.
// g folded into W, b folded into bias3 by prep kernels.
// ---------------------------------------------------------------------------
__global__ __launch_bounds__(256, 2) void k_ln_qkv(
    const float* __restrict__ x,
    const unsigned short* __restrict__ wqkv_p, const float* __restrict__ bias3,
    float* __restrict__ q, float* __restrict__ k, float* __restrict__ v)
{
    const int t = threadIdx.x;
    const int lane = t & 63, wave = t >> 6;
    const int nl = lane & 15, quad = lane >> 4;
    const int nbase = blockIdx.x * 64 + wave * 16;
    const int node = nbase + nl;
    const bool nv = node < NN;

    float xv[64];
    float sum = 0.f, sq = 0.f;
    {
        const float* xp = x + (size_t)node * H + quad * 8;
        #pragma unroll
        for (int ks = 0; ks < 8; ++ks) {
            float4 x0 = {0.f,0.f,0.f,0.f}, x1 = {0.f,0.f,0.f,0.f};
            if (nv) {
                x0 = *(const float4*)(xp + ks * 32);
                x1 = *(const float4*)(xp + ks * 32 + 4);
            }
            xv[ks*8+0]=x0.x; xv[ks*8+1]=x0.y; xv[ks*8+2]=x0.z; xv[ks*8+3]=x0.w;
            xv[ks*8+4]=x1.x; xv[ks*8+5]=x1.y; xv[ks*8+6]=x1.z; xv[ks*8+7]=x1.w;
            sum += x0.x+x0.y+x0.z+x0.w + x1.x+x1.y+x1.z+x1.w;
            sq  += x0.x*x0.x+x0.y*x0.y+x0.z*x0.z+x0.w*x0.w
                 + x1.x*x1.x+x1.y*x1.y+x1.z*x1.z+x1.w*x1.w;
        }
    }
    // row sum across the 4 quads holding this node's chunks
    sum += __shfl_xor(sum, 16); sum += __shfl_xor(sum, 32);
    sq  += __shfl_xor(sq, 16);  sq  += __shfl_xor(sq, 32);
    const float mu  = sum * (1.0f / H);
    const float var = sq * (1.0f / H) - mu * mu;
    const float rs  = rsqrtf(var + LN_EPS);

    short8 a_hi[8], a_lo[8];
    #pragma unroll
    for (int ks = 0; ks < 8; ++ks) {
        #pragma unroll
        for (int j = 0; j < 8; ++j) {
            const float z = (xv[ks*8+j] - mu) * rs;
            const unsigned short hh = f2bf(z);
            a_hi[ks][j] = (short)hh;
            a_lo[ks][j] = (short)f2bf(z - bf2f(hh));
        }
    }

    for (int mat = 0; mat < 3; ++mat) {
        float* outp = mat == 0 ? q : (mat == 1 ? k : v);
        const float* bp = bias3 + mat * 256;
        const unsigned short* wb = wqkv_p + (size_t)mat * 131072 + lane * 8;
        for (int tile = 0; tile < 16; ++tile) {
            const unsigned short* gb = wb + (size_t)tile * 8192;
            const float bbv = bp[tile * 16 + nl];
            f32x4 acc = {bbv, bbv, bbv, bbv};
            #pragma unroll
            for (int ks = 0; ks < 8; ++ks) {
                const short8 b_hi = *(const short8*)(gb + ks * 1024);
                const short8 b_lo = *(const short8*)(gb + ks * 1024 + 512);
                acc = __builtin_amdgcn_mfma_f32_16x16x32_bf16(a_hi[ks], b_hi, acc, 0, 0, 0);
                acc = __builtin_amdgcn_mfma_f32_16x16x32_bf16(a_lo[ks], b_hi, acc, 0, 0, 0);
                acc = __builtin_amdgcn_mfma_f32_16x16x32_bf16(a_hi[ks], b_lo, acc, 0, 0, 0);
            }
            #pragma unroll
            for (int r = 0; r < 4; ++r) {
                const int onode = nbase + quad * 4 + r;
                if (onode < NN)
                    outp[(size_t)onode * H + tile * 16 + nl] = acc[r];
            }
        }
    }
}

// ---------------------------------------------------------------------------
// Counting sort of edges by dst: hist -> 3-phase scan -> scatter(perm)
// ---------------------------------------------------------------------------
__global__ __launch_bounds__(256) void k_hist(const int* __restrict__ ei, int* __restrict__ hist) {
    int e = blockIdx.x * 256 + threadIdx.x;
    if (e < EE) atomicAdd(&hist[ei[EE + e]], 1);
}

__global__ __launch_bounds__(256) void k_scan1(const int* __restrict__ hist,
                                               int* __restrict__ cursor, int* __restrict__ bsum) {
    const int t = threadIdx.x, i = blockIdx.x * 256 + t;
    const int lane = t & 63, w = t >> 6;
    const int v = (i < NN) ? hist[i] : 0;
    int incl = v;
    #pragma unroll
    for (int off = 1; off < 64; off <<= 1) {
        int u = __shfl_up(incl, off);
        if (lane >= off) incl += u;
    }
    __shared__ int ws[4];
    if (lane == 63) ws[w] = incl;
    __syncthreads();
    int base = 0;
    #pragma unroll
    for (int j = 0; j < 4; ++j) if (j < w) base += ws[j];
    if (i < NN) cursor[i] = base + incl - v;
    if (t == 255) bsum[blockIdx.x] = base + incl;
}

__global__ __launch_bounds__(128) void k_scan2(int* __restrict__ bsum) {
    __shared__ int buf[128];
    const int t = threadIdx.x;
    const int v = (t < NB) ? bsum[t] : 0;
    buf[t] = v;
    __syncthreads();
    #pragma unroll
    for (int off = 1; off < 128; off <<= 1) {
        int add = (t >= off) ? buf[t - off] : 0;
        __syncthreads();
        buf[t] += add;
        __syncthreads();
    }
    if (t < NB) bsum[t] = buf[t] - v;
}

__global__ __launch_bounds__(256) void k_scan3(int* __restrict__ cursor, const int* __restrict__ bsum) {
    const int i = blockIdx.x * 256 + threadIdx.x;
    if (i < NN) cursor[i] += bsum[blockIdx.x];
}

__global__ __launch_bounds__(256) void k_scatter(const int* __restrict__ ei,
                                                 int* __restrict__ cursor, int* __restrict__ perm) {
    int e = blockIdx.x * 256 + threadIdx.x;
    if (e < EE) {
        int d = ei[EE + e];
        int pos = atomicAdd(&cursor[d], 1);
        perm[pos] = e;
    }
}

// ---------------------------------------------------------------------------
// K2: sorted-edge kernel. MFMA core + coalesced epilogues (proven round 5);
// weight staging is now an identity 16B copy from the prepped swizzled image.
// ---------------------------------------------------------------------------
__global__ __launch_bounds__(256, 3) void k_edge(
    const float* __restrict__ q, const float* __restrict__ k, const float* __restrict__ v,
    const int* __restrict__ ei, const float* __restrict__ ew, const float* __restrict__ ea,
    const unsigned short* __restrict__ wdk_p, const float* __restrict__ bdk,
    const unsigned short* __restrict__ wdv_p, const float* __restrict__ bdv,
    const int* __restrict__ perm,
    float* __restrict__ agg)
{
    __shared__ unsigned short ea_hi_s[64 * 64], ea_lo_s[64 * 64];   //  8+8 KB
    __shared__ unsigned short w_region[2 * 128 * 64];               // 32 KB
    __shared__ float attn_s[64];
    __shared__ int src_s[64], dst_s[64];

    unsigned short* w_hi_s = w_region;
    unsigned short* w_lo_s = w_region + 128 * 64;
    float* dks = (float*)w_region;                                  // [64][128] f32

    const int t    = threadIdx.x;
    const int eb   = blockIdx.x * 64;
    const int lane = t & 63, wave = t >> 6;
    const int nl   = lane & 15, quad = lane >> 4;
    const int estrip = wave * 16;
    const int tx = t & 31, ty = t >> 5;
    const int h0 = tx * 4, e0 = ty * 8;

    if (t < 64) {
        const int e = perm[eb + t];
        src_s[t] = ei[e];
        dst_s[t] = ei[EE + e];
        attn_s[t] = 0.f;
    }
    {   // stage ea tile with on-the-fly hi/lo split; 4 threads per edge row
        const int row = t >> 2, seg = t & 3;
        const int e = perm[eb + row];
        const float* sp = ea + (size_t)e * R + seg * 16;
        #pragma unroll
        for (int j = 0; j < 4; ++j) {
            const float4 x4 = *(const float4*)(sp + 4 * j);
            const int di = sw_idx(row, seg * 16 + 4 * j);
            const unsigned short a0 = f2bf(x4.x), a1 = f2bf(x4.y),
                                 a2 = f2bf(x4.z), a3 = f2bf(x4.w);
            ushort4 hi4 = {a0, a1, a2, a3};
            ushort4 lo4 = {f2bf(x4.x - bf2f(a0)), f2bf(x4.y - bf2f(a1)),
                           f2bf(x4.z - bf2f(a2)), f2bf(x4.w - bf2f(a3))};
            *(ushort4*)&ea_hi_s[di] = hi4;
            *(ushort4*)&ea_lo_s[di] = lo4;
        }
    }
    __syncthreads();

    short8 a_hi[2], a_lo[2];
    {
        const int arow = estrip + nl;
        #pragma unroll
        for (int ks = 0; ks < 2; ++ks) {
            const int idx = arow * 64 + ((((ks * 4 + quad) ^ (nl & 7)) << 3));
            a_hi[ks] = *(const short8*)&ea_hi_s[idx];
            a_lo[ks] = *(const short8*)&ea_lo_s[idx];
        }
    }

    // ---------------- pass A: attention logits ----------------
    for (int hh = 0; hh < 2; ++hh) {
        __syncthreads();
        {   // identity copy of prepped 32KB half image into w_region
            const ushort8* sp = (const ushort8*)(wdk_p + (size_t)hh * 16384) + t;
            ushort8* dp = (ushort8*)w_region + t;
            #pragma unroll
            for (int c = 0; c < 8; ++c) dp[c * 256] = sp[c * 256];
        }
        __syncthreads();

        f32x4 accA[8];
        #pragma unroll
        for (int tt = 0; tt < 8; ++tt) {
            const int wrow = tt * 16 + nl;
            const int hcol = hh * 128 + tt * 16 + nl;
            short8 b_hi[2], b_lo[2];
            #pragma unroll
            for (int ks = 0; ks < 2; ++ks) {
                const int idx = wrow * 64 + ((((ks * 4 + quad) ^ (nl & 7)) << 3));
                b_hi[ks] = *(const short8*)&w_hi_s[idx];
                b_lo[ks] = *(const short8*)&w_lo_s[idx];
            }
            const float bb = bdk[hcol];
            f32x4 acc = {bb, bb, bb, bb};
            #pragma unroll
            for (int ks = 0; ks < 2; ++ks) {
                acc = __builtin_amdgcn_mfma_f32_16x16x32_bf16(a_hi[ks], b_hi[ks], acc, 0, 0, 0);
                acc = __builtin_amdgcn_mfma_f32_16x16x32_bf16(a_lo[ks], b_hi[ks], acc, 0, 0, 0);
                acc = __builtin_amdgcn_mfma_f32_16x16x32_bf16(a_hi[ks], b_lo[ks], acc, 0, 0, 0);
            }
            accA[tt] = acc;
        }
        __syncthreads();
        #pragma unroll
        for (int tt = 0; tt < 8; ++tt)
            #pragma unroll
            for (int r = 0; r < 4; ++r)
                dks[dk_idx(estrip + quad * 4 + r, tt * 16 + nl)] = silu_f(accA[tt][r]);
        __syncthreads();

        #pragma unroll
        for (int i = 0; i < 8; ++i) {
            const int d = dst_s[e0 + i], s = src_s[e0 + i];
            const float4 qi  = *(const float4*)(q + (size_t)d * H + hh * 128 + h0);
            const float4 kj  = *(const float4*)(k + (size_t)s * H + hh * 128 + h0);
            const float4 dk4 = *(const float4*)&dks[dk_idx(e0 + i, h0)];
            float part = qi.x * kj.x * dk4.x + qi.y * kj.y * dk4.y
                       + qi.z * kj.z * dk4.z + qi.w * kj.w * dk4.w;
            #pragma unroll
            for (int off = 16; off; off >>= 1) part += __shfl_xor(part, off);
            if (tx == 0) attn_s[e0 + i] += part;
        }
    }
    __syncthreads();
    if (t < 64) {
        const int e = perm[eb + t];
        const float rr = ew[e];
        const float cut = (rr < 5.0f) ? 0.5f * (__cosf(rr * 0.6283185307f) + 1.0f) : 0.0f;
        attn_s[t] = silu_f(attn_s[t]) * cut;
    }

    // ---------------- pass B: messages + run-flush scatter ----------------
    for (int hh = 0; hh < 2; ++hh) {
        __syncthreads();
        {
            const ushort8* sp = (const ushort8*)(wdv_p + (size_t)hh * 16384) + t;
            ushort8* dp = (ushort8*)w_region + t;
            #pragma unroll
            for (int c = 0; c < 8; ++c) dp[c * 256] = sp[c * 256];
        }
        __syncthreads();

        f32x4 accA[8];
        #pragma unroll
        for (int tt = 0; tt < 8; ++tt) {
            const int wrow = tt * 16 + nl;
            const int hcol = hh * 128 + tt * 16 + nl;
            short8 b_hi[2], b_lo[2];
            #pragma unroll
            for (int ks = 0; ks < 2; ++ks) {
                const int idx = wrow * 64 + ((((ks * 4 + quad) ^ (nl & 7)) << 3));
                b_hi[ks] = *(const short8*)&w_hi_s[idx];
                b_lo[ks] = *(const short8*)&w_lo_s[idx];
            }
            const float bb = bdv[hcol];
            f32x4 acc = {bb, bb, bb, bb};
            #pragma unroll
            for (int ks = 0; ks < 2; ++ks) {
                acc = __builtin_amdgcn_mfma_f32_16x16x32_bf16(a_hi[ks], b_hi[ks], acc, 0, 0, 0);
                acc = __builtin_amdgcn_mfma_f32_16x16x32_bf16(a_lo[ks], b_hi[ks], acc, 0, 0, 0);
                acc = __builtin_amdgcn_mfma_f32_16x16x32_bf16(a_hi[ks], b_lo[ks], acc, 0, 0, 0);
            }
            accA[tt] = acc;
        }
        __syncthreads();
        #pragma unroll
        for (int tt = 0; tt < 8; ++tt)
            #pragma unroll
            for (int r = 0; r < 4; ++r)
                dks[dk_idx(estrip + quad * 4 + r, tt * 16 + nl)] = silu_f(accA[tt][r]);
        __syncthreads();

        float4 m = {0.f, 0.f, 0.f, 0.f};
        int cur_d = -1;
        #pragma unroll
        for (int i = 0; i < 8; ++i) {
            const int d = dst_s[e0 + i], s = src_s[e0 + i];
            const float a = attn_s[e0 + i];
            const float4 vj  = *(const float4*)(v + (size_t)s * H + hh * 128 + h0);
            const float4 dv4 = *(const float4*)&dks[dk_idx(e0 + i, h0)];
            float4 mi;
            mi.x = vj.x * dv4.x * a;
            mi.y = vj.y * dv4.y * a;
            mi.z = vj.z * dv4.z * a;
            mi.w = vj.w * dv4.w * a;
            if (d != cur_d) {
                if (cur_d >= 0) {
                    float* dp = agg + (size_t)cur_d * H + hh * 128 + h0;
                    atomicAdd(dp + 0, m.x); atomicAdd(dp + 1, m.y);
                    atomicAdd(dp + 2, m.z); atomicAdd(dp + 3, m.w);
                }
                m = mi; cur_d = d;
            } else {
                m.x += mi.x; m.y += mi.y; m.z += mi.z; m.w += mi.w;
            }
        }
        {
            float* dp = agg + (size_t)cur_d * H + hh * 128 + h0;
            atomicAdd(dp + 0, m.x); atomicAdd(dp + 1, m.y);
            atomicAdd(dp + 2, m.z); atomicAdd(dp + 3, m.w);
        }
    }
}

// ---------------------------------------------------------------------------
// K3: out = x + agg @ Wo'^T + bo via split-bf16 MFMA. Same structure as K1.
// ---------------------------------------------------------------------------
__global__ __launch_bounds__(256, 2) void k_out(
    const float* __restrict__ aggm, const unsigned short* __restrict__ wo_p,
    const float* __restrict__ bo, const float* __restrict__ x, float* __restrict__ out)
{
    const int t = threadIdx.x;
    const int lane = t & 63, wave = t >> 6;
    const int nl = lane & 15, quad = lane >> 4;
    const int nbase = blockIdx.x * 64 + wave * 16;
    const int node = nbase + nl;
    const bool nv = node < NN;

    short8 a_hi[8], a_lo[8];
    {
        const float* ap = aggm + (size_t)node * H + quad * 8;
        #pragma unroll
        for (int ks = 0; ks < 8; ++ks) {
            float4 x0 = {0.f,0.f,0.f,0.f}, x1 = {0.f,0.f,0.f,0.f};
            if (nv) { x0 = *(const float4*)(ap + ks * 32); x1 = *(const float4*)(ap + ks * 32 + 4); }
            const float zz[8] = {x0.x,x0.y,x0.z,x0.w,x1.x,x1.y,x1.z,x1.w};
            #pragma unroll
            for (int j = 0; j < 8; ++j) {
                const unsigned short hh = f2bf(zz[j]);
                a_hi[ks][j] = (short)hh;
                a_lo[ks][j] = (short)f2bf(zz[j] - bf2f(hh));
            }
        }
    }
    for (int tile = 0; tile < 16; ++tile) {
        const unsigned short* gb = wo_p + (size_t)tile * 8192 + lane * 8;
        const float bbv = bo[tile * 16 + nl];
        f32x4 acc = {bbv, bbv, bbv, bbv};
        #pragma unroll
        for (int ks = 0; ks < 8; ++ks) {
            const short8 b_hi = *(const short8*)(gb + ks * 1024);
            const short8 b_lo = *(const short8*)(gb + ks * 1024 + 512);
            acc = __builtin_amdgcn_mfma_f32_16x16x32_bf16(a_hi[ks], b_hi, acc, 0, 0, 0);
            acc = __builtin_amdgcn_mfma_f32_16x16x32_bf16(a_lo[ks], b_hi, acc, 0, 0, 0);
            acc = __builtin_amdgcn_mfma_f32_16x16x32_bf16(a_hi[ks], b_lo, acc, 0, 0, 0);
        }
        #pragma unroll
        for (int r = 0; r < 4; ++r) {
            const int onode = nbase + quad * 4 + r;
            if (onode < NN) {
                const size_t oi = (size_t)onode * H + tile * 16 + nl;
                out[oi] = x[oi] + acc[r];
            }
        }
    }
}

extern "C" void kernel_launch(void* const* d_in, const int* in_sizes, int n_in,
                              void* d_out, int out_size, void* d_ws, size_t ws_size,
                              hipStream_t stream) {
    const float* x   = (const float*)d_in[0];
    const int*   ei  = (const int*)d_in[1];
    const float* ew  = (const float*)d_in[2];
    const float* ea  = (const float*)d_in[3];
    const float* g   = (const float*)d_in[4];
    const float* b   = (const float*)d_in[5];
    const float* Wq  = (const float*)d_in[6];  const float* bq  = (const float*)d_in[7];
    const float* Wk  = (const float*)d_in[8];  const float* bk  = (const float*)d_in[9];
    const float* Wv  = (const float*)d_in[10]; const float* bv  = (const float*)d_in[11];
    const float* Wo  = (const float*)d_in[12]; const float* bo  = (const float*)d_in[13];
    const float* Wdk = (const float*)d_in[14]; const float* bdk = (const float*)d_in[15];
    const float* Wdv = (const float*)d_in[16]; const float* bdv = (const float*)d_in[17];

    float* q    = (float*)d_ws;
    float* k    = q + (size_t)NN * H;
    float* v    = k + (size_t)NN * H;
    float* agg  = v + (size_t)NN * H;
    int*   hist = (int*)(agg + (size_t)NN * H);
    int*   cur  = hist + NN;
    int*   bsum = cur + NN;
    int*   perm = bsum + 128;
    unsigned short* wqkv_p = (unsigned short*)(perm + EE);
    unsigned short* wo_p   = wqkv_p + 393216;
    unsigned short* wdk_p  = wo_p + 131072;
    unsigned short* wdv_p  = wdk_p + 32768;
    float* bias3 = (float*)(wdv_p + 32768);

    hipMemsetAsync(hist, 0, NN * sizeof(int), stream);
    hipMemsetAsync(agg, 0, (size_t)NN * H * sizeof(float), stream);
    k_prep_w<<<32, 256, 0, stream>>>(Wq, g, 1, wqkv_p);
    k_prep_w<<<32, 256, 0, stream>>>(Wk, g, 1, wqkv_p + 131072);
    k_prep_w<<<32, 256, 0, stream>>>(Wv, g, 1, wqkv_p + 262144);
    k_prep_w<<<32, 256, 0, stream>>>(Wo, g, 0, wo_p);
    k_prep_wdx<<<32, 256, 0, stream>>>(Wdk, Wdv, wdk_p, wdv_p);
    k_prep_bias<<<3, 256, 0, stream>>>(b, Wq, bq, Wk, bk, Wv, bv, bias3);
    k_hist<<<EE / 256, 256, 0, stream>>>(ei, hist);
    k_ln_qkv<<<(NN + 63) / 64, 256, 0, stream>>>(x, wqkv_p, bias3, q, k, v);
    k_scan1<<<NB, 256, 0, stream>>>(hist, cur, bsum);
    k_scan2<<<1, 128, 0, stream>>>(bsum);
    k_scan3<<<NB, 256, 0, stream>>>(cur, bsum);
    k_scatter<<<EE / 256, 256, 0, stream>>>(ei, cur, perm);
    k_edge<<<EE / 64, 256, 0, stream>>>(q, k, v, ei, ew, ea, wdk_p, bdk, wdv_p, bdv, perm, agg);
    k_out<<<(NN + 63) / 64, 256, 0, stream>>>(agg, wo_p, bo, x, (float*)d_out);
}

// Round 7
// 648.420 us; speedup vs baseline: 1.4713x; 1.0284x over previous
//
#include <hip/hip_runtime.h>
#include <math.h>

#define NN 20000
#define H 256
#define R 64
#define EE 320000
#define LN_EPS 1e-5f
#define NB 79   // ceil(NN/256)

using short8  = __attribute__((ext_vector_type(8))) short;
using ushort8 = __attribute__((ext_vector_type(8))) unsigned short;
using f32x4   = __attribute__((ext_vector_type(4))) float;

__device__ __forceinline__ float silu_f(float x) { return x / (1.0f + __expf(-x)); }

// round-to-nearest-even fp32 -> bf16 (as ushort)
__device__ __forceinline__ unsigned short f2bf(float f) {
    unsigned u = __float_as_uint(f);
    u += 0x7fff + ((u >> 16) & 1);
    return (unsigned short)(u >> 16);
}
__device__ __forceinline__ float bf2f(unsigned short s) {
    return __uint_as_float(((unsigned)s) << 16);
}

// XOR-swizzled LDS index for [row][64] short arrays (bf16 fragments)
__device__ __forceinline__ int sw_idx(int row, int col) {
    return row * 64 + ((((col >> 3) ^ (row & 7)) << 3) | (col & 7));
}
// dk/dv scratch [64][128] f32: xor bit4 of col by row-bit2 -> 2-way max on C-store
__device__ __forceinline__ int dk_idx(int row, int col) {
    return row * 128 + (col ^ (((row >> 2) & 1) << 4));
}

// ---------------------------------------------------------------------------
// Combined prep (one launch, 163 blocks):
//  blocks [0,128): pack Wq/Wk/Wv (g folded) + Wo into MFMA B-fragment order
//  blocks [128,160): pack Wdk/Wdv into the swizzled LDS image k_edge copies
//  blocks [160,163): adjusted QKV biases bias3[m][h] = b_m[h] + sum_c b[c]W_m[h][c]
// ---------------------------------------------------------------------------
__global__ __launch_bounds__(256) void k_prep(
    const float* __restrict__ Wq, const float* __restrict__ Wk,
    const float* __restrict__ Wv, const float* __restrict__ Wo,
    const float* __restrict__ g,  const float* __restrict__ b,
    const float* __restrict__ bq, const float* __restrict__ bk, const float* __restrict__ bv,
    const float* __restrict__ Wdk, const float* __restrict__ Wdv,
    unsigned short* __restrict__ wqkv_p, unsigned short* __restrict__ wo_p,
    unsigned short* __restrict__ wdk_p,  unsigned short* __restrict__ wdv_p,
    float* __restrict__ bias3)
{
    const int bid = blockIdx.x, t = threadIdx.x;
    if (bid < 128) {
        const int mat = bid >> 5;
        const float* W = mat == 0 ? Wq : (mat == 1 ? Wk : (mat == 2 ? Wv : Wo));
        unsigned short* out = (mat < 3) ? wqkv_p + (size_t)mat * 131072 : wo_p;
        const int fold = mat < 3;
        const int flat = (bid & 31) * 256 + t;           // [0, 8192)
        const int tile = flat >> 9;
        const int rem  = flat & 511;
        const int ks   = rem >> 6;
        const int lane = rem & 63;
        const int nl = lane & 15, quad = lane >> 4;
        const int h  = tile * 16 + nl;
        const int c0 = ks * 32 + quad * 8;
        short8 hi8, lo8;
        #pragma unroll
        for (int j = 0; j < 8; ++j) {
            float wv = W[(size_t)h * 256 + c0 + j];
            if (fold) wv *= g[c0 + j];
            const unsigned short hh = f2bf(wv);
            hi8[j] = (short)hh;
            lo8[j] = (short)f2bf(wv - bf2f(hh));
        }
        unsigned short* ob = out + ((size_t)(tile * 8 + ks)) * 1024;
        *(short8*)&ob[lane * 8] = hi8;
        *(short8*)&ob[512 + lane * 8] = lo8;
    } else if (bid < 160) {
        const int flat = (bid - 128) * 256 + t;          // [0, 8192)
        const int mat  = flat >> 12;
        const int rem  = flat & 4095;
        const int hh   = rem >> 11;
        const int r2   = rem & 2047;
        const int row  = r2 >> 4;
        const int col4 = (r2 & 15) * 4;
        const float* W = mat == 0 ? Wdk : Wdv;
        unsigned short* out = (mat == 0 ? wdk_p : wdv_p) + hh * 16384;
        const float4 w4 = *(const float4*)(W + (size_t)(hh * 128 + row) * 64 + col4);
        const unsigned short h0 = f2bf(w4.x), h1 = f2bf(w4.y), h2 = f2bf(w4.z), h3 = f2bf(w4.w);
        ushort4 hi4 = {h0, h1, h2, h3};
        ushort4 lo4 = {f2bf(w4.x - bf2f(h0)), f2bf(w4.y - bf2f(h1)),
                       f2bf(w4.z - bf2f(h2)), f2bf(w4.w - bf2f(h3))};
        const int di = sw_idx(row, col4);
        *(ushort4*)&out[di] = hi4;
        *(ushort4*)&out[8192 + di] = lo4;
    } else {
        const int mat = bid - 160, h = t;
        const float* W  = mat == 0 ? Wq : (mat == 1 ? Wk : Wv);
        const float* bb = mat == 0 ? bq : (mat == 1 ? bk : bv);
        float s = 0.f;
        const float* wr = W + (size_t)h * 256;
        for (int c = 0; c < 256; c += 4) {
            const float4 w4 = *(const float4*)(wr + c);
            const float4 b4 = *(const float4*)(b + c);
            s += w4.x * b4.x + w4.y * b4.y + w4.z * b4.z + w4.w * b4.w;
        }
        bias3[mat * 256 + h] = bb[h] + s;
    }
}

// ---------------------------------------------------------------------------
// K1: LayerNorm + QKV via split-bf16 MFMA. 64 nodes/block (16/wave), no LDS.
// ---------------------------------------------------------------------------
__global__ __launch_bounds__(256, 2) void k_ln_qkv(
    const float* __restrict__ x,
    const unsigned short* __restrict__ wqkv_p, const float* __restrict__ bias3,
    float* __restrict__ q, float* __restrict__ k, float* __restrict__ v)
{
    const int t = threadIdx.x;
    const int lane = t & 63, wave = t >> 6;
    const int nl = lane & 15, quad = lane >> 4;
    const int nbase = blockIdx.x * 64 + wave * 16;
    const int node = nbase + nl;
    const bool nv = node < NN;

    float xv[64];
    float sum = 0.f, sq = 0.f;
    {
        const float* xp = x + (size_t)node * H + quad * 8;
        #pragma unroll
        for (int ks = 0; ks < 8; ++ks) {
            float4 x0 = {0.f,0.f,0.f,0.f}, x1 = {0.f,0.f,0.f,0.f};
            if (nv) {
                x0 = *(const float4*)(xp + ks * 32);
                x1 = *(const float4*)(xp + ks * 32 + 4);
            }
            xv[ks*8+0]=x0.x; xv[ks*8+1]=x0.y; xv[ks*8+2]=x0.z; xv[ks*8+3]=x0.w;
            xv[ks*8+4]=x1.x; xv[ks*8+5]=x1.y; xv[ks*8+6]=x1.z; xv[ks*8+7]=x1.w;
            sum += x0.x+x0.y+x0.z+x0.w + x1.x+x1.y+x1.z+x1.w;
            sq  += x0.x*x0.x+x0.y*x0.y+x0.z*x0.z+x0.w*x0.w
                 + x1.x*x1.x+x1.y*x1.y+x1.z*x1.z+x1.w*x1.w;
        }
    }
    sum += __shfl_xor(sum, 16); sum += __shfl_xor(sum, 32);
    sq  += __shfl_xor(sq, 16);  sq  += __shfl_xor(sq, 32);
    const float mu  = sum * (1.0f / H);
    const float var = sq * (1.0f / H) - mu * mu;
    const float rs  = rsqrtf(var + LN_EPS);

    short8 a_hi[8], a_lo[8];
    #pragma unroll
    for (int ks = 0; ks < 8; ++ks) {
        #pragma unroll
        for (int j = 0; j < 8; ++j) {
            const float z = (xv[ks*8+j] - mu) * rs;
            const unsigned short hh = f2bf(z);
            a_hi[ks][j] = (short)hh;
            a_lo[ks][j] = (short)f2bf(z - bf2f(hh));
        }
    }

    for (int mat = 0; mat < 3; ++mat) {
        float* outp = mat == 0 ? q : (mat == 1 ? k : v);
        const float* bp = bias3 + mat * 256;
        const unsigned short* wb = wqkv_p + (size_t)mat * 131072 + lane * 8;
        for (int tile = 0; tile < 16; ++tile) {
            const unsigned short* gb = wb + (size_t)tile * 8192;
            const float bbv = bp[tile * 16 + nl];
            f32x4 acc = {bbv, bbv, bbv, bbv};
            #pragma unroll
            for (int ks = 0; ks < 8; ++ks) {
                const short8 b_hi = *(const short8*)(gb + ks * 1024);
                const short8 b_lo = *(const short8*)(gb + ks * 1024 + 512);
                acc = __builtin_amdgcn_mfma_f32_16x16x32_bf16(a_hi[ks], b_hi, acc, 0, 0, 0);
                acc = __builtin_amdgcn_mfma_f32_16x16x32_bf16(a_lo[ks], b_hi, acc, 0, 0, 0);
                acc = __builtin_amdgcn_mfma_f32_16x16x32_bf16(a_hi[ks], b_lo, acc, 0, 0, 0);
            }
            #pragma unroll
            for (int r = 0; r < 4; ++r) {
                const int onode = nbase + quad * 4 + r;
                if (onode < NN)
                    outp[(size_t)onode * H + tile * 16 + nl] = acc[r];
            }
        }
    }
}

// ---------------------------------------------------------------------------
// Counting sort of edges by dst: hist -> 3-phase scan -> scatter(perm)
// ---------------------------------------------------------------------------
__global__ __launch_bounds__(256) void k_hist(const int* __restrict__ ei, int* __restrict__ hist) {
    int e = blockIdx.x * 256 + threadIdx.x;
    if (e < EE) atomicAdd(&hist[ei[EE + e]], 1);
}

__global__ __launch_bounds__(256) void k_scan1(const int* __restrict__ hist,
                                               int* __restrict__ cursor, int* __restrict__ bsum) {
    const int t = threadIdx.x, i = blockIdx.x * 256 + t;
    const int lane = t & 63, w = t >> 6;
    const int v = (i < NN) ? hist[i] : 0;
    int incl = v;
    #pragma unroll
    for (int off = 1; off < 64; off <<= 1) {
        int u = __shfl_up(incl, off);
        if (lane >= off) incl += u;
    }
    __shared__ int ws[4];
    if (lane == 63) ws[w] = incl;
    __syncthreads();
    int base = 0;
    #pragma unroll
    for (int j = 0; j < 4; ++j) if (j < w) base += ws[j];
    if (i < NN) cursor[i] = base + incl - v;
    if (t == 255) bsum[blockIdx.x] = base + incl;
}

__global__ __launch_bounds__(128) void k_scan2(int* __restrict__ bsum) {
    __shared__ int buf[128];
    const int t = threadIdx.x;
    const int v = (t < NB) ? bsum[t] : 0;
    buf[t] = v;
    __syncthreads();
    #pragma unroll
    for (int off = 1; off < 128; off <<= 1) {
        int add = (t >= off) ? buf[t - off] : 0;
        __syncthreads();
        buf[t] += add;
        __syncthreads();
    }
    if (t < NB) bsum[t] = buf[t] - v;
}

__global__ __launch_bounds__(256) void k_scan3(int* __restrict__ cursor, const int* __restrict__ bsum) {
    const int i = blockIdx.x * 256 + threadIdx.x;
    if (i < NN) cursor[i] += bsum[blockIdx.x];
}

__global__ __launch_bounds__(256) void k_scatter(const int* __restrict__ ei,
                                                 int* __restrict__ cursor, int* __restrict__ perm) {
    int e = blockIdx.x * 256 + threadIdx.x;
    if (e < EE) {
        int d = ei[EE + e];
        int pos = atomicAdd(&cursor[d], 1);
        perm[pos] = e;
    }
}

// ---------------------------------------------------------------------------
// K2: sorted-edge kernel (round-5/6 proven core) + XCD-aware chunk swizzle:
// block bi handles edge chunk (bi&7)*625 + (bi>>3), so with round-robin
// dispatch XCD x owns a CONTIGUOUS sorted-edge range -> all scatter atomics
// for a given dst issue from one XCD (except 7 seams); agg lines stay in
// that XCD's L2 instead of ping-ponging (round 6: 230 MB HBM writes for a
// 20.5 MB agg). q[dst] gathers gain the same L2 locality.
// ---------------------------------------------------------------------------
__global__ __launch_bounds__(256, 3) void k_edge(
    const float* __restrict__ q, const float* __restrict__ k, const float* __restrict__ v,
    const int* __restrict__ ei, const float* __restrict__ ew, const float* __restrict__ ea,
    const unsigned short* __restrict__ wdk_p, const float* __restrict__ bdk,
    const unsigned short* __restrict__ wdv_p, const float* __restrict__ bdv,
    const int* __restrict__ perm,
    float* __restrict__ agg)
{
    __shared__ unsigned short ea_hi_s[64 * 64], ea_lo_s[64 * 64];   //  8+8 KB
    __shared__ unsigned short w_region[2 * 128 * 64];               // 32 KB
    __shared__ float attn_s[64];
    __shared__ int src_s[64], dst_s[64];

    unsigned short* w_hi_s = w_region;
    unsigned short* w_lo_s = w_region + 128 * 64;
    float* dks = (float*)w_region;                                  // [64][128] f32

    const int t    = threadIdx.x;
    const int bi   = blockIdx.x;
    const int eb   = ((bi & 7) * 625 + (bi >> 3)) * 64;   // XCD-contiguous chunks
    const int lane = t & 63, wave = t >> 6;
    const int nl   = lane & 15, quad = lane >> 4;
    const int estrip = wave * 16;
    const int tx = t & 31, ty = t >> 5;
    const int h0 = tx * 4, e0 = ty * 8;

    if (t < 64) {
        const int e = perm[eb + t];
        src_s[t] = ei[e];
        dst_s[t] = ei[EE + e];
        attn_s[t] = 0.f;
    }
    {   // stage ea tile with on-the-fly hi/lo split; 4 threads per edge row
        const int row = t >> 2, seg = t & 3;
        const int e = perm[eb + row];
        const float* sp = ea + (size_t)e * R + seg * 16;
        #pragma unroll
        for (int j = 0; j < 4; ++j) {
            const float4 x4 = *(const float4*)(sp + 4 * j);
            const int di = sw_idx(row, seg * 16 + 4 * j);
            const unsigned short a0 = f2bf(x4.x), a1 = f2bf(x4.y),
                                 a2 = f2bf(x4.z), a3 = f2bf(x4.w);
            ushort4 hi4 = {a0, a1, a2, a3};
            ushort4 lo4 = {f2bf(x4.x - bf2f(a0)), f2bf(x4.y - bf2f(a1)),
                           f2bf(x4.z - bf2f(a2)), f2bf(x4.w - bf2f(a3))};
            *(ushort4*)&ea_hi_s[di] = hi4;
            *(ushort4*)&ea_lo_s[di] = lo4;
        }
    }
    __syncthreads();

    short8 a_hi[2], a_lo[2];
    {
        const int arow = estrip + nl;
        #pragma unroll
        for (int ks = 0; ks < 2; ++ks) {
            const int idx = arow * 64 + ((((ks * 4 + quad) ^ (nl & 7)) << 3));
            a_hi[ks] = *(const short8*)&ea_hi_s[idx];
            a_lo[ks] = *(const short8*)&ea_lo_s[idx];
        }
    }

    // ---------------- pass A: attention logits ----------------
    for (int hh = 0; hh < 2; ++hh) {
        __syncthreads();
        {   // identity copy of prepped 32KB half image into w_region
            const ushort8* sp = (const ushort8*)(wdk_p + (size_t)hh * 16384) + t;
            ushort8* dp = (ushort8*)w_region + t;
            #pragma unroll
            for (int c = 0; c < 8; ++c) dp[c * 256] = sp[c * 256];
        }
        __syncthreads();

        f32x4 accA[8];
        #pragma unroll
        for (int tt = 0; tt < 8; ++tt) {
            const int wrow = tt * 16 + nl;
            const int hcol = hh * 128 + tt * 16 + nl;
            short8 b_hi[2], b_lo[2];
            #pragma unroll
            for (int ks = 0; ks < 2; ++ks) {
                const int idx = wrow * 64 + ((((ks * 4 + quad) ^ (nl & 7)) << 3));
                b_hi[ks] = *(const short8*)&w_hi_s[idx];
                b_lo[ks] = *(const short8*)&w_lo_s[idx];
            }
            const float bb = bdk[hcol];
            f32x4 acc = {bb, bb, bb, bb};
            #pragma unroll
            for (int ks = 0; ks < 2; ++ks) {
                acc = __builtin_amdgcn_mfma_f32_16x16x32_bf16(a_hi[ks], b_hi[ks], acc, 0, 0, 0);
                acc = __builtin_amdgcn_mfma_f32_16x16x32_bf16(a_lo[ks], b_hi[ks], acc, 0, 0, 0);
                acc = __builtin_amdgcn_mfma_f32_16x16x32_bf16(a_hi[ks], b_lo[ks], acc, 0, 0, 0);
            }
            accA[tt] = acc;
        }
        __syncthreads();
        #pragma unroll
        for (int tt = 0; tt < 8; ++tt)
            #pragma unroll
            for (int r = 0; r < 4; ++r)
                dks[dk_idx(estrip + quad * 4 + r, tt * 16 + nl)] = silu_f(accA[tt][r]);
        __syncthreads();

        #pragma unroll
        for (int i = 0; i < 8; ++i) {
            const int d = dst_s[e0 + i], s = src_s[e0 + i];
            const float4 qi  = *(const float4*)(q + (size_t)d * H + hh * 128 + h0);
            const float4 kj  = *(const float4*)(k + (size_t)s * H + hh * 128 + h0);
            const float4 dk4 = *(const float4*)&dks[dk_idx(e0 + i, h0)];
            float part = qi.x * kj.x * dk4.x + qi.y * kj.y * dk4.y
                       + qi.z * kj.z * dk4.z + qi.w * kj.w * dk4.w;
            #pragma unroll
            for (int off = 16; off; off >>= 1) part += __shfl_xor(part, off);
            if (tx == 0) attn_s[e0 + i] += part;
        }
    }
    __syncthreads();
    if (t < 64) {
        const int e = perm[eb + t];
        const float rr = ew[e];
        const float cut = (rr < 5.0f) ? 0.5f * (__cosf(rr * 0.6283185307f) + 1.0f) : 0.0f;
        attn_s[t] = silu_f(attn_s[t]) * cut;
    }

    // ---------------- pass B: messages + run-flush scatter ----------------
    for (int hh = 0; hh < 2; ++hh) {
        __syncthreads();
        {
            const ushort8* sp = (const ushort8*)(wdv_p + (size_t)hh * 16384) + t;
            ushort8* dp = (ushort8*)w_region + t;
            #pragma unroll
            for (int c = 0; c < 8; ++c) dp[c * 256] = sp[c * 256];
        }
        __syncthreads();

        f32x4 accA[8];
        #pragma unroll
        for (int tt = 0; tt < 8; ++tt) {
            const int wrow = tt * 16 + nl;
            const int hcol = hh * 128 + tt * 16 + nl;
            short8 b_hi[2], b_lo[2];
            #pragma unroll
            for (int ks = 0; ks < 2; ++ks) {
                const int idx = wrow * 64 + ((((ks * 4 + quad) ^ (nl & 7)) << 3));
                b_hi[ks] = *(const short8*)&w_hi_s[idx];
                b_lo[ks] = *(const short8*)&w_lo_s[idx];
            }
            const float bb = bdv[hcol];
            f32x4 acc = {bb, bb, bb, bb};
            #pragma unroll
            for (int ks = 0; ks < 2; ++ks) {
                acc = __builtin_amdgcn_mfma_f32_16x16x32_bf16(a_hi[ks], b_hi[ks], acc, 0, 0, 0);
                acc = __builtin_amdgcn_mfma_f32_16x16x32_bf16(a_lo[ks], b_hi[ks], acc, 0, 0, 0);
                acc = __builtin_amdgcn_mfma_f32_16x16x32_bf16(a_hi[ks], b_lo[ks], acc, 0, 0, 0);
            }
            accA[tt] = acc;
        }
        __syncthreads();
        #pragma unroll
        for (int tt = 0; tt < 8; ++tt)
            #pragma unroll
            for (int r = 0; r < 4; ++r)
                dks[dk_idx(estrip + quad * 4 + r, tt * 16 + nl)] = silu_f(accA[tt][r]);
        __syncthreads();

        float4 m = {0.f, 0.f, 0.f, 0.f};
        int cur_d = -1;
        #pragma unroll
        for (int i = 0; i < 8; ++i) {
            const int d = dst_s[e0 + i], s = src_s[e0 + i];
            const float a = attn_s[e0 + i];
            const float4 vj  = *(const float4*)(v + (size_t)s * H + hh * 128 + h0);
            const float4 dv4 = *(const float4*)&dks[dk_idx(e0 + i, h0)];
            float4 mi;
            mi.x = vj.x * dv4.x * a;
            mi.y = vj.y * dv4.y * a;
            mi.z = vj.z * dv4.z * a;
            mi.w = vj.w * dv4.w * a;
            if (d != cur_d) {
                if (cur_d >= 0) {
                    float* dp = agg + (size_t)cur_d * H + hh * 128 + h0;
                    atomicAdd(dp + 0, m.x); atomicAdd(dp + 1, m.y);
                    atomicAdd(dp + 2, m.z); atomicAdd(dp + 3, m.w);
                }
                m = mi; cur_d = d;
            } else {
                m.x += mi.x; m.y += mi.y; m.z += mi.z; m.w += mi.w;
            }
        }
        {
            float* dp = agg + (size_t)cur_d * H + hh * 128 + h0;
            atomicAdd(dp + 0, m.x); atomicAdd(dp + 1, m.y);
            atomicAdd(dp + 2, m.z); atomicAdd(dp + 3, m.w);
        }
    }
}

// ---------------------------------------------------------------------------
// K3: out = x + agg @ Wo'^T + bo via split-bf16 MFMA.
// ---------------------------------------------------------------------------
__global__ __launch_bounds__(256, 2) void k_out(
    const float* __restrict__ aggm, const unsigned short* __restrict__ wo_p,
    const float* __restrict__ bo, const float* __restrict__ x, float* __restrict__ out)
{
    const int t = threadIdx.x;
    const int lane = t & 63, wave = t >> 6;
    const int nl = lane & 15, quad = lane >> 4;
    const int nbase = blockIdx.x * 64 + wave * 16;
    const int node = nbase + nl;
    const bool nv = node < NN;

    short8 a_hi[8], a_lo[8];
    {
        const float* ap = aggm + (size_t)node * H + quad * 8;
        #pragma unroll
        for (int ks = 0; ks < 8; ++ks) {
            float4 x0 = {0.f,0.f,0.f,0.f}, x1 = {0.f,0.f,0.f,0.f};
            if (nv) { x0 = *(const float4*)(ap + ks * 32); x1 = *(const float4*)(ap + ks * 32 + 4); }
            const float zz[8] = {x0.x,x0.y,x0.z,x0.w,x1.x,x1.y,x1.z,x1.w};
            #pragma unroll
            for (int j = 0; j < 8; ++j) {
                const unsigned short hh = f2bf(zz[j]);
                a_hi[ks][j] = (short)hh;
                a_lo[ks][j] = (short)f2bf(zz[j] - bf2f(hh));
            }
        }
    }
    for (int tile = 0; tile < 16; ++tile) {
        const unsigned short* gb = wo_p + (size_t)tile * 8192 + lane * 8;
        const float bbv = bo[tile * 16 + nl];
        f32x4 acc = {bbv, bbv, bbv, bbv};
        #pragma unroll
        for (int ks = 0; ks < 8; ++ks) {
            const short8 b_hi = *(const short8*)(gb + ks * 1024);
            const short8 b_lo = *(const short8*)(gb + ks * 1024 + 512);
            acc = __builtin_amdgcn_mfma_f32_16x16x32_bf16(a_hi[ks], b_hi, acc, 0, 0, 0);
            acc = __builtin_amdgcn_mfma_f32_16x16x32_bf16(a_lo[ks], b_hi, acc, 0, 0, 0);
            acc = __builtin_amdgcn_mfma_f32_16x16x32_bf16(a_hi[ks], b_lo, acc, 0, 0, 0);
        }
        #pragma unroll
        for (int r = 0; r < 4; ++r) {
            const int onode = nbase + quad * 4 + r;
            if (onode < NN) {
                const size_t oi = (size_t)onode * H + tile * 16 + nl;
                out[oi] = x[oi] + acc[r];
            }
        }
    }
}

extern "C" void kernel_launch(void* const* d_in, const int* in_sizes, int n_in,
                              void* d_out, int out_size, void* d_ws, size_t ws_size,
                              hipStream_t stream) {
    const float* x   = (const float*)d_in[0];
    const int*   ei  = (const int*)d_in[1];
    const float* ew  = (const float*)d_in[2];
    const float* ea  = (const float*)d_in[3];
    const float* g   = (const float*)d_in[4];
    const float* b   = (const float*)d_in[5];
    const float* Wq  = (const float*)d_in[6];  const float* bq  = (const float*)d_in[7];
    const float* Wk  = (const float*)d_in[8];  const float* bk  = (const float*)d_in[9];
    const float* Wv  = (const float*)d_in[10]; const float* bv  = (const float*)d_in[11];
    const float* Wo  = (const float*)d_in[12]; const float* bo  = (const float*)d_in[13];
    const float* Wdk = (const float*)d_in[14]; const float* bdk = (const float*)d_in[15];
    const float* Wdv = (const float*)d_in[16]; const float* bdv = (const float*)d_in[17];

    float* q    = (float*)d_ws;
    float* k    = q + (size_t)NN * H;
    float* v    = k + (size_t)NN * H;
    float* agg  = v + (size_t)NN * H;
    int*   hist = (int*)(agg + (size_t)NN * H);
    int*   cur  = hist + NN;
    int*   bsum = cur + NN;
    int*   perm = bsum + 128;
    unsigned short* wqkv_p = (unsigned short*)(perm + EE);
    unsigned short* wo_p   = wqkv_p + 393216;
    unsigned short* wdk_p  = wo_p + 131072;
    unsigned short* wdv_p  = wdk_p + 32768;
    float* bias3 = (float*)(wdv_p + 32768);

    hipMemsetAsync(hist, 0, NN * sizeof(int), stream);
    hipMemsetAsync(agg, 0, (size_t)NN * H * sizeof(float), stream);
    k_prep<<<163, 256, 0, stream>>>(Wq, Wk, Wv, Wo, g, b, bq, bk, bv, Wdk, Wdv,
                                    wqkv_p, wo_p, wdk_p, wdv_p, bias3);
    k_hist<<<EE / 256, 256, 0, stream>>>(ei, hist);
    k_ln_qkv<<<(NN + 63) / 64, 256, 0, stream>>>(x, wqkv_p, bias3, q, k, v);
    k_scan1<<<NB, 256, 0, stream>>>(hist, cur, bsum);
    k_scan2<<<1, 128, 0, stream>>>(bsum);
    k_scan3<<<NB, 256, 0, stream>>>(cur, bsum);
    k_scatter<<<EE / 256, 256, 0, stream>>>(ei, cur, perm);
    k_edge<<<EE / 64, 256, 0, stream>>>(q, k, v, ei, ew, ea, wdk_p, bdk, wdv_p, bdv, perm, agg);
    k_out<<<(NN + 63) / 64, 256, 0, stream>>>(agg, wo_p, bo, x, (float*)d_out);
}